// Round 5
// baseline (513.903 us; speedup 1.0000x reference)
//
#include <hip/hip_runtime.h>
#include <hip/hip_bf16.h>
#include <hip/hip_cooperative_groups.h>

namespace cg = cooperative_groups;

typedef __bf16 bf16;
typedef __bf16 bf16x4 __attribute__((ext_vector_type(4)));
typedef __bf16 bf16x8 __attribute__((ext_vector_type(8)));
typedef float f32x4 __attribute__((ext_vector_type(4)));
typedef _Float16 half4 __attribute__((ext_vector_type(4)));

// B=4, T=8, L=512, D=512, H=8, E=64.  BT=32, BTH=256, M=BT*L=16384.

#if __has_builtin(__builtin_amdgcn_exp2f)
#define EXP2(x) __builtin_amdgcn_exp2f(x)
#else
#define EXP2(x) exp2f(x)
#endif

static __device__ __forceinline__ f32x4 mfma16(bf16x4 a, bf16x4 b, f32x4 c) {
#if __has_builtin(__builtin_amdgcn_mfma_f32_16x16x16bf16_1k)
    return __builtin_amdgcn_mfma_f32_16x16x16bf16_1k(a, b, c, 0, 0, 0);
#else
    asm("v_mfma_f32_16x16x16_bf16 %0, %1, %2, %0" : "+v"(c) : "v"(a), "v"(b));
    return c;
#endif
}

// ===========================================================================
// Phase bodies (shared between mega kernel and 4-dispatch fallback).
// All use <= 36,864 B of the caller's shared buffer.  Bodies are identical
// math to the R2-verified kernels (proj v1, attn v9 no-setprio, f16 partials).
// ===========================================================================

// prep W job 0..191: W[d][n] fp32 -> Wt[z][n][d] bf16 (64x64 tile transpose)
static __device__ __forceinline__ void prep_w_job(int job, const float* W0,
                                                  const float* W1, const float* W2,
                                                  bf16* Wt, char* sraw) {
    float(*t)[65] = (float(*)[65])sraw;  // 64*65*4 = 16,640 B
    __syncthreads();  // guard: LDS may be in use by a previous job/phase
    const int z = job >> 6, sub = job & 63;
    const float* W = (z == 0) ? W0 : (z == 1) ? W1 : W2;
    bf16* O = Wt + (size_t)z * 512 * 512;
    const int d0 = (sub & 7) * 64, n0 = (sub >> 3) * 64;
    {
        int nl = threadIdx.x & 63, dg = threadIdx.x >> 6;
#pragma unroll
        for (int j = 0; j < 16; ++j) {
            int dl = dg + j * 4;
            t[nl][dl] = W[(size_t)(d0 + dl) * 512 + n0 + nl];
        }
    }
    __syncthreads();
    {
        int dl = threadIdx.x & 63, ng = threadIdx.x >> 6;
#pragma unroll
        for (int j = 0; j < 16; ++j) {
            int nl = ng + j * 4;
            O[(size_t)(n0 + nl) * 512 + d0 + dl] = (bf16)t[nl][dl];
        }
    }
}

// prep mask job 0..63: mask (512,512) f32 -> Mp bf16 in attn per-lane order:
//   Mp[((qg*8+c)*4+ns)*256 + lane*4 + r] = mask[qg*16+lc][c*64+ns*16+quad*4+r]
static __device__ __forceinline__ void prep_mask_job(int bid, const float* maskf,
                                                     bf16* Mp) {
    const int t0 = bid * 256 + threadIdx.x;
    const float4* m4 = (const float4*)maskf;
#pragma unroll
    for (int j = 0; j < 4; ++j) {
        int idx = t0 + j * 16384;   // float4 index 0..65535 (coalesced read)
        int q = idx >> 7;           // row
        int sc = idx & 127;         // float4-col
        int cc = sc >> 4;           // chunk 0..7
        int ns = (sc >> 2) & 3;
        int qd = sc & 3;            // quad
        float4 v = m4[idx];
        bf16x4 o;
        o[0] = (bf16)v.x; o[1] = (bf16)v.y; o[2] = (bf16)v.z; o[3] = (bf16)v.w;
        size_t off = ((((size_t)(q >> 4) * 8 + cc) * 4 + ns) * 4 + qd) * 64 +
                     (q & 15) * 4;
        *(bf16x4*)&Mp[off] = o;
    }
}

// proj job 0..1535 (z = j/512, bid = j%512): 128x128 tile GEMM, BK=64,
// v1 structure (2 barriers/step, 36,864 B LDS, register prefetch).
// XCD swizzle: the 4 n-tiles of one m-tile run adjacently on one XCD.
static __device__ __forceinline__ void proj_job(int j, const float* __restrict__ Xq,
                                                const float* __restrict__ Xk,
                                                const float* __restrict__ Xv,
                                                const bf16* __restrict__ Wt,
                                                bf16* __restrict__ Qw,
                                                bf16* __restrict__ Kw,
                                                bf16* __restrict__ Vt, char* sraw) {
    bf16* smem = (bf16*)sraw;     // 18432 bf16 = 36,864 B
    bf16* la = smem;              // [m][k] 128x72
    bf16* lb = smem + 9216;       // [n][k] 128x72

    const int z = j >> 9, bid = j & 511;
    const float* X = (z == 0) ? Xq : (z == 1) ? Xk : Xv;
    const bf16* W  = Wt + (size_t)z * 512 * 512;
    bf16* Out      = (z == 0) ? Qw : (z == 1) ? Kw : Vt;

    const int tid = threadIdx.x, wave = tid >> 6, lane = tid & 63;
    const int quad = lane >> 4, lc = lane & 15;
    const int wm = wave & 1, wn = wave >> 1;
    const int jj = bid >> 3;
    const int yy = jj & 3;                      // n-tile (fastest per XCD)
    const int xt = (bid & 7) * 16 + (jj >> 2);  // m-tile
    const int m0 = xt * 128, n0 = yy * 128;

    f32x4 acc[4][4];
#pragma unroll
    for (int ms = 0; ms < 4; ++ms)
#pragma unroll
        for (int ns = 0; ns < 4; ++ns) acc[ms][ns] = (f32x4){0.f, 0.f, 0.f, 0.f};

    const int ar = tid >> 4, ac = tid & 15;
    const int br = tid >> 3, bc = tid & 7;

    float4 xr[8];
    bf16x8 wr[4];
#pragma unroll
    for (int i = 0; i < 8; ++i)
        xr[i] = *(const float4*)&X[(size_t)(m0 + ar + i * 16) * 512 + ac * 4];
#pragma unroll
    for (int i = 0; i < 4; ++i)
        wr[i] = *(const bf16x8*)&W[(size_t)(n0 + br + i * 32) * 512 + bc * 8];

    for (int kb = 0; kb < 512; kb += 64) {
        __syncthreads();
#pragma unroll
        for (int i = 0; i < 8; ++i) {
            float4 x = xr[i];
            bf16x4 p;
            p[0] = (bf16)x.x; p[1] = (bf16)x.y; p[2] = (bf16)x.z; p[3] = (bf16)x.w;
            *(bf16x4*)&la[(ar + i * 16) * 72 + ac * 4] = p;
        }
#pragma unroll
        for (int i = 0; i < 4; ++i)
            *(bf16x8*)&lb[(br + i * 32) * 72 + bc * 8] = wr[i];
        __syncthreads();
        if (kb < 448) {
            int kn = kb + 64;
#pragma unroll
            for (int i = 0; i < 8; ++i)
                xr[i] = *(const float4*)&X[(size_t)(m0 + ar + i * 16) * 512 + kn + ac * 4];
#pragma unroll
            for (int i = 0; i < 4; ++i)
                wr[i] = *(const bf16x8*)&W[(size_t)(n0 + br + i * 32) * 512 + kn + bc * 8];
        }
#pragma unroll
        for (int kk = 0; kk < 2; ++kk) {
            bf16x8 af[4], bfr[4];
#pragma unroll
            for (int ms = 0; ms < 4; ++ms)
                af[ms] = *(bf16x8*)&la[(wm * 64 + ms * 16 + lc) * 72 + kk * 32 + quad * 8];
#pragma unroll
            for (int ns = 0; ns < 4; ++ns)
                bfr[ns] = *(bf16x8*)&lb[(wn * 64 + ns * 16 + lc) * 72 + kk * 32 + quad * 8];
#pragma unroll
            for (int ms = 0; ms < 4; ++ms)
#pragma unroll
                for (int ns = 0; ns < 4; ++ns)
                    acc[ms][ns] = __builtin_amdgcn_mfma_f32_16x16x32_bf16(
                        af[ms], bfr[ns], acc[ms][ns], 0, 0, 0);
        }
    }
    // --- epilogue ---
    __syncthreads();
    bf16* lds_c = smem;  // z<2: [m][n] 128x136 ; z==2: [n][m] 128x136 (34,816 B)
    if (z != 2) {
#pragma unroll
        for (int ms = 0; ms < 4; ++ms)
#pragma unroll
            for (int ns = 0; ns < 4; ++ns)
#pragma unroll
                for (int r = 0; r < 4; ++r)
                    lds_c[(wm * 64 + ms * 16 + quad * 4 + r) * 136 +
                          wn * 64 + ns * 16 + lc] = (bf16)acc[ms][ns][r];
    } else {
#pragma unroll
        for (int ms = 0; ms < 4; ++ms)
#pragma unroll
            for (int ns = 0; ns < 4; ++ns)
#pragma unroll
                for (int r = 0; r < 4; ++r)
                    lds_c[(wn * 64 + ns * 16 + lc) * 136 +
                          wm * 64 + ms * 16 + quad * 4 + r] = (bf16)acc[ms][ns][r];
    }
    __syncthreads();
    const int bt = m0 >> 9, l0 = m0 & 511;
    if (z != 2) {
        const int ec = tid & 7, rg = tid >> 3;
#pragma unroll
        for (int hc = 0; hc < 2; ++hc) {
            int h = (n0 >> 6) + hc;
#pragma unroll
            for (int p = 0; p < 4; ++p) {
                int row = rg + p * 32;
                bf16x8 v = *(bf16x8*)&lds_c[row * 136 + hc * 64 + ec * 8];
                *(bf16x8*)&Out[(((size_t)bt * 8 + h) * 512 + l0 + row) * 64 + ec * 8] = v;
            }
        }
    } else {
        const int rowp = lane >> 2, cc = lane & 3;
#pragma unroll
        for (int pr = 0; pr < 2; ++pr) {
            int row = wave * 32 + pr * 16 + rowp;  // n_local 0..127
            int h = (n0 >> 6) + (row >> 6);
            int e = row & 63;
            bf16* dst = Out + (((size_t)bt * 8 + h) * 64 + e) * 512 + l0;
#pragma unroll
            for (int pc = 0; pc < 4; ++pc) {
                int mc = cc + pc * 4;
                *(bf16x8*)&dst[mc * 8] = *(bf16x8*)&lds_c[row * 136 + mc * 8];
            }
        }
    }
}

// attn job 0..1023: wave owns 32 q-rows (2 q-tiles); mask pre-layout;
// in-register P->PV via 16x16x16; K/V double-buffer, 1 barrier/chunk.
// mode 0: atomicAdd into out (fallback).  mode 2: f16 partials into Op.
static __device__ __forceinline__ void attn_job(
    int b, const bf16* __restrict__ Qw, const bf16* __restrict__ Kw,
    const bf16* __restrict__ Vt, const bf16* __restrict__ Mp,
    const float* __restrict__ w_head, const float* __restrict__ tau,
    const float* __restrict__ delta, float* __restrict__ out,
    _Float16* __restrict__ Op, int mode, char* sraw) {
    bf16* ldsK = (bf16*)sraw;          // [2][64*72]
    bf16* ldsV = (bf16*)sraw + 9216;   // [2][64*72]
    __syncthreads();  // guard: prior phase/job may still be reading LDS

    const int tid  = threadIdx.x;
    const int wave = tid >> 6;
    const int lane = tid & 63;
    const int quad = lane >> 4;
    const int lc   = lane & 15;
    const int bth  = b & 255;
    const int qquad = b >> 8;  // 0..3
    const int bt   = bth >> 3;
    const int h    = bth & 7;

    const bf16* Qh  = Qw + (size_t)bth * (512 * 64);
    const bf16* Kh  = Kw + (size_t)bth * (512 * 64);
    const bf16* VtH = Vt + (size_t)bth * (512 * 64);  // [e][s]

    const float L2E = 1.4426950408889634f;
    const float ts = tau[0] * 0.125f * L2E;
    const float ds = delta[0] * 0.125f * L2E;
    const float wh = w_head[h];

    const int q0 = qquad * 128 + wave * 32;
    const size_t mbA = (size_t)(q0 >> 4) * 8192 + lane * 4;
    const size_t mbB = mbA + 8192;

    bf16x8 qfA[2], qfB[2];
#pragma unroll
    for (int kk = 0; kk < 2; ++kk) {
        qfA[kk] = *(const bf16x8*)&Qh[(size_t)(q0 + lc) * 64 + kk * 32 + quad * 8];
        qfB[kk] = *(const bf16x8*)&Qh[(size_t)(q0 + 16 + lc) * 64 + kk * 32 + quad * 8];
    }

    f32x4 oA[4], oB[4];
#pragma unroll
    for (int ns = 0; ns < 4; ++ns) {
        oA[ns] = (f32x4){0.f, 0.f, 0.f, 0.f};
        oB[ns] = (f32x4){0.f, 0.f, 0.f, 0.f};
    }
    float lA = 0.f, lB = 0.f;

    const int srow = tid >> 3, scc = tid & 7;
    bf16x8 kr[2], vr[2];
    kr[0] = *(const bf16x8*)&Kh[(size_t)srow * 64 + scc * 8];
    kr[1] = *(const bf16x8*)&Kh[(size_t)(srow + 32) * 64 + scc * 8];
    vr[0] = *(const bf16x8*)&VtH[(size_t)srow * 512 + scc * 8];
    vr[1] = *(const bf16x8*)&VtH[(size_t)(srow + 32) * 512 + scc * 8];
    *(bf16x8*)&ldsK[srow * 72 + scc * 8] = kr[0];
    *(bf16x8*)&ldsK[(srow + 32) * 72 + scc * 8] = kr[1];
    *(bf16x8*)&ldsV[srow * 72 + scc * 8] = vr[0];
    *(bf16x8*)&ldsV[(srow + 32) * 72 + scc * 8] = vr[1];
    kr[0] = *(const bf16x8*)&Kh[(size_t)(64 + srow) * 64 + scc * 8];
    kr[1] = *(const bf16x8*)&Kh[(size_t)(64 + srow + 32) * 64 + scc * 8];
    vr[0] = *(const bf16x8*)&VtH[(size_t)srow * 512 + 64 + scc * 8];
    vr[1] = *(const bf16x8*)&VtH[(size_t)(srow + 32) * 512 + 64 + scc * 8];

    for (int c = 0; c < 8; ++c) {
        const int buf = c & 1;
        bf16* lk = ldsK + buf * 4608;
        bf16* lv = ldsV + buf * 4608;
        __syncthreads();  // buf staged (prologue or end of body c-1)
        bf16x4 mA[4], mB[4];
        {
            const size_t mc = mbA + (size_t)c * 1024;
            const size_t md = mbB + (size_t)c * 1024;
#pragma unroll
            for (int ns = 0; ns < 4; ++ns) {
                mA[ns] = *(const bf16x4*)&Mp[mc + ns * 256];
                mB[ns] = *(const bf16x4*)&Mp[md + ns * 256];
            }
        }
        f32x4 stA[4], stB[4];
#pragma unroll
        for (int ns = 0; ns < 4; ++ns) {
            stA[ns] = (f32x4){0.f, 0.f, 0.f, 0.f};
            stB[ns] = (f32x4){0.f, 0.f, 0.f, 0.f};
        }
#pragma unroll
        for (int kk = 0; kk < 2; ++kk)
#pragma unroll
            for (int ns = 0; ns < 4; ++ns) {
                bf16x8 ka = *(bf16x8*)&lk[(ns * 16 + lc) * 72 + kk * 32 + quad * 8];
                stA[ns] = __builtin_amdgcn_mfma_f32_16x16x32_bf16(ka, qfA[kk], stA[ns], 0, 0, 0);
                stB[ns] = __builtin_amdgcn_mfma_f32_16x16x32_bf16(ka, qfB[kk], stB[ns], 0, 0, 0);
            }
        if (c < 7) {
            bf16* lkn = ldsK + (buf ^ 1) * 4608;
            bf16* lvn = ldsV + (buf ^ 1) * 4608;
            *(bf16x8*)&lkn[srow * 72 + scc * 8] = kr[0];
            *(bf16x8*)&lkn[(srow + 32) * 72 + scc * 8] = kr[1];
            *(bf16x8*)&lvn[srow * 72 + scc * 8] = vr[0];
            *(bf16x8*)&lvn[(srow + 32) * 72 + scc * 8] = vr[1];
            if (c < 6) {
                const int s0n = (c + 2) * 64;
                kr[0] = *(const bf16x8*)&Kh[(size_t)(s0n + srow) * 64 + scc * 8];
                kr[1] = *(const bf16x8*)&Kh[(size_t)(s0n + srow + 32) * 64 + scc * 8];
                vr[0] = *(const bf16x8*)&VtH[(size_t)srow * 512 + s0n + scc * 8];
                vr[1] = *(const bf16x8*)&VtH[(size_t)(srow + 32) * 512 + s0n + scc * 8];
            }
        }
        bf16x4 paA[4], paB[4];
#pragma unroll
        for (int ns = 0; ns < 4; ++ns) {
#pragma unroll
            for (int r = 0; r < 4; ++r) {
                float eA = (stA[ns][r] * ts + ds) * (float)mA[ns][r];
                float eB = (stB[ns][r] * ts + ds) * (float)mB[ns][r];
                float pA = EXP2(eA);
                float pB = EXP2(eB);
                lA += pA; lB += pB;
                paA[ns][r] = (bf16)pA;
                paB[ns][r] = (bf16)pB;
            }
        }
#pragma unroll
        for (int ks = 0; ks < 4; ++ks)
#pragma unroll
            for (int ns = 0; ns < 4; ++ns) {
                bf16x4 vv = *(bf16x4*)&lv[(ns * 16 + lc) * 72 + ks * 16 + quad * 4];
                oA[ns] = mfma16(paA[ks], vv, oA[ns]);
                oB[ns] = mfma16(paB[ks], vv, oB[ns]);
            }
    }
    // epilogue
    lA += __shfl_xor(lA, 16, 64);
    lA += __shfl_xor(lA, 32, 64);
    lB += __shfl_xor(lB, 16, 64);
    lB += __shfl_xor(lB, 32, 64);
#pragma unroll
    for (int r = 0; r < 4; ++r) {
        float lrA = __shfl(lA, quad * 4 + r, 64);
        float lrB = __shfl(lB, quad * 4 + r, 64);
        float ivA = wh / lrA, ivB = wh / lrB;
        int qqA = q0 + quad * 4 + r;
        int qqB = q0 + 16 + quad * 4 + r;
        if (mode == 0) {
#pragma unroll
            for (int ns = 0; ns < 4; ++ns) {
                int e = ns * 16 + lc;
                atomicAdd(&out[((size_t)bt * 512 + qqA) * 64 + e], oA[ns][r] * ivA);
                atomicAdd(&out[((size_t)bt * 512 + qqB) * 64 + e], oB[ns][r] * ivB);
            }
        } else {
#pragma unroll
            for (int ns = 0; ns < 4; ++ns) {
                int e = ns * 16 + lc;
                Op[((size_t)bth * 512 + qqA) * 64 + e] = (_Float16)(oA[ns][r] * ivA);
                Op[((size_t)bth * 512 + qqB) * 64 + e] = (_Float16)(oB[ns][r] * ivB);
            }
        }
    }
}

// reduce element idx (float4 units): out = sum_h Opart[bt*8+h]
static __device__ __forceinline__ void reduce_one(int idx, const _Float16* __restrict__ Op,
                                                  float* __restrict__ out) {
    const int bt = idx >> 13, rf = idx & 8191;
    const half4* p = (const half4*)Op + (size_t)bt * 65536 + rf;
    f32x4 s = (f32x4){0.f, 0.f, 0.f, 0.f};
#pragma unroll
    for (int h = 0; h < 8; ++h) {
        half4 v = p[(size_t)h * 8192];
        s[0] += (float)v[0]; s[1] += (float)v[1];
        s[2] += (float)v[2]; s[3] += (float)v[3];
    }
    *(f32x4*)&out[(size_t)idx * 4] = s;
}

// ===========================================================================
// MEGA: prep -> proj -> attn -> reduce in ONE cooperative dispatch.
// Grid sized by the runtime-validated occupancy (cooperative launch errors,
// never hangs, if the grid exceeds resident capacity).  36,864 B LDS;
// bounds (256,4) => 4 blocks/CU => up to 1024 co-resident blocks.
// ===========================================================================
__global__ __launch_bounds__(256, 4) void mega_kernel(
    const float* __restrict__ Xq, const float* __restrict__ Xk,
    const float* __restrict__ Xv, const float* __restrict__ maskf,
    const float* __restrict__ Wq, const float* __restrict__ Wk,
    const float* __restrict__ Wv, const float* __restrict__ w_head,
    const float* __restrict__ tau, const float* __restrict__ delta,
    float* __restrict__ out, bf16* __restrict__ Qw, bf16* __restrict__ Kw,
    bf16* __restrict__ Vt, bf16* __restrict__ Wt, bf16* __restrict__ Mp,
    _Float16* __restrict__ Op) {
    __shared__ __align__(16) char sraw[36864];
    cg::grid_group grid = cg::this_grid();
    const int G = (int)gridDim.x;

    // phase 0: weight transpose (192 jobs) + mask pre-layout (64 jobs)
    for (int j = (int)blockIdx.x; j < 256; j += G) {
        if (j < 192) prep_w_job(j, Wq, Wk, Wv, Wt, sraw);
        else         prep_mask_job(j - 192, maskf, Mp);
    }
    grid.sync();
    // phase 1: projections (1536 jobs)
    for (int j = (int)blockIdx.x; j < 1536; j += G)
        proj_job(j, Xq, Xk, Xv, Wt, Qw, Kw, Vt, sraw);
    grid.sync();
    // phase 2: attention (1024 jobs), f16 partials
    for (int j = (int)blockIdx.x; j < 1024; j += G)
        attn_job(j, Qw, Kw, Vt, Mp, w_head, tau, delta, out, Op, 2, sraw);
    grid.sync();
    // phase 3: head reduction (262,144 float4)
    for (int i = (int)blockIdx.x * 256 + (int)threadIdx.x; i < 262144; i += G * 256)
        reduce_one(i, Op, out);
}

// ===========================================================================
// Fallback 4-dispatch kernels (used if cooperative launch unavailable)
// ===========================================================================
__global__ __launch_bounds__(256) void prep_kernel(const float* W0, const float* W1,
                                                   const float* W2, const float* maskf,
                                                   bf16* Wt, bf16* Mp) {
    __shared__ __align__(16) char sraw[36864];
    if (blockIdx.z == 3) {
        prep_mask_job(blockIdx.y * 8 + blockIdx.x, maskf, Mp);
        return;
    }
    prep_w_job(blockIdx.z * 64 + blockIdx.y * 8 + blockIdx.x, W0, W1, W2, Wt, sraw);
}

__global__ __launch_bounds__(256) void proj_kernel(const float* Xq, const float* Xk,
                                                   const float* Xv, const bf16* Wt,
                                                   bf16* Qw, bf16* Kw, bf16* Vt) {
    __shared__ __align__(16) char sraw[36864];
    int j = blockIdx.z * 512 + blockIdx.y * 128 + blockIdx.x;
    proj_job(j, Xq, Xk, Xv, Wt, Qw, Kw, Vt, sraw);
}

__global__ __launch_bounds__(256, 4) void attn_kernel(const bf16* Qw, const bf16* Kw,
                                                      const bf16* Vt, const bf16* Mp,
                                                      const float* w_head, const float* tau,
                                                      const float* delta, float* out,
                                                      _Float16* Op, int mode) {
    __shared__ __align__(16) char sraw[36864];
    attn_job(blockIdx.x, Qw, Kw, Vt, Mp, w_head, tau, delta, out, Op, mode, sraw);
}

__global__ __launch_bounds__(256) void reduce_kernel(const _Float16* Op, float* out) {
    reduce_one(blockIdx.x * 256 + threadIdx.x, Op, out);
}

// ---------------------------------------------------------------------------
extern "C" void kernel_launch(void* const* d_in, const int* in_sizes, int n_in,
                              void* d_out, int out_size, void* d_ws, size_t ws_size,
                              hipStream_t stream) {
    const float* queries = (const float*)d_in[0];
    const float* keys    = (const float*)d_in[1];
    const float* values  = (const float*)d_in[2];
    const float* mask    = (const float*)d_in[3];
    const float* Wq      = (const float*)d_in[4];
    const float* Wk      = (const float*)d_in[5];
    const float* Wv      = (const float*)d_in[6];
    const float* w_head  = (const float*)d_in[7];
    const float* tau     = (const float*)d_in[8];
    const float* delta   = (const float*)d_in[9];

    char* ws = (char*)d_ws;
    bf16* Qw = (bf16*)(ws);                          // 16,777,216 B
    bf16* Kw = (bf16*)(ws + 16777216ull);            // 16,777,216 B
    bf16* Vt = (bf16*)(ws + 33554432ull);            // 16,777,216 B (V^T)
    bf16* Wt = (bf16*)(ws + 50331648ull);            //  1,572,864 B
    bf16* Mp = (bf16*)(ws + 51904512ull);            //    524,288 B
    _Float16* Op = (_Float16*)(ws + 52428800ull);    // 16,777,216 B (f16 partials)
    float* outp = (float*)d_out;
    const size_t need_mega = 52428800ull + 16777216ull;

    // One-time capability probe: cooperative-launch support + real occupancy.
    // (Attribute/occupancy queries only — no allocations, capture-safe.)
    static int s_grid = -2;
    if (s_grid == -2) {
        int dev = 0, coop = 0, cus = 0, mb = 0;
        (void)hipGetDevice(&dev);
        (void)hipDeviceGetAttribute(&coop, hipDeviceAttributeCooperativeLaunch, dev);
        (void)hipDeviceGetAttribute(&cus, hipDeviceAttributeMultiprocessorCount, dev);
        if (coop && cus > 0 &&
            hipOccupancyMaxActiveBlocksPerMultiprocessor(&mb, mega_kernel, 256, 0) ==
                hipSuccess &&
            mb > 0) {
            long g = (long)mb * (long)cus;
            if (g > 1024) g = 1024;
            s_grid = (int)g;
        } else {
            s_grid = 0;
        }
    }

    if (ws_size >= need_mega && s_grid >= 256) {
        void* params[] = {(void*)&queries, (void*)&keys,   (void*)&values,
                          (void*)&mask,    (void*)&Wq,     (void*)&Wk,
                          (void*)&Wv,      (void*)&w_head, (void*)&tau,
                          (void*)&delta,   (void*)&outp,   (void*)&Qw,
                          (void*)&Kw,      (void*)&Vt,     (void*)&Wt,
                          (void*)&Mp,      (void*)&Op};
        hipError_t e = hipLaunchCooperativeKernel(mega_kernel, dim3(s_grid),
                                                  dim3(256), params, 0, stream);
        if (e == hipSuccess) return;
        (void)hipGetLastError();  // clear; fall through to 4-dispatch path
        s_grid = 0;               // don't retry cooperative on later calls
    }

    // fallback: 4-dispatch path (R2-verified)
    int mode = (ws_size >= need_mega) ? 2 : 0;
    if (mode == 0)
        hipMemsetAsync(d_out, 0, (size_t)out_size * sizeof(float), stream);
    prep_kernel<<<dim3(8, 8, 4), 256, 0, stream>>>(Wq, Wk, Wv, mask, Wt, Mp);
    proj_kernel<<<dim3(128, 4, 3), 256, 0, stream>>>(queries, keys, values, Wt,
                                                     Qw, Kw, Vt);
    attn_kernel<<<1024, 256, 0, stream>>>(Qw, Kw, Vt, Mp, w_head, tau, delta,
                                          (float*)d_out, Op, mode);
    if (mode != 0)
        reduce_kernel<<<1024, 256, 0, stream>>>(Op, (float*)d_out);
}

// Round 6
// 228.230 us; speedup vs baseline: 2.2517x; 2.2517x over previous
//
#include <hip/hip_runtime.h>
#include <hip/hip_bf16.h>

typedef __bf16 bf16;
typedef __bf16 bf16x4 __attribute__((ext_vector_type(4)));
typedef __bf16 bf16x8 __attribute__((ext_vector_type(8)));
typedef float f32x4 __attribute__((ext_vector_type(4)));
typedef _Float16 half4 __attribute__((ext_vector_type(4)));

// B=4, T=8, L=512, D=512, H=8, E=64.  BT=32, BTH=256, M=BT*L=16384.

#if __has_builtin(__builtin_amdgcn_exp2f)
#define EXP2(x) __builtin_amdgcn_exp2f(x)
#else
#define EXP2(x) exp2f(x)
#endif

static __device__ __forceinline__ f32x4 mfma16(bf16x4 a, bf16x4 b, f32x4 c) {
#if __has_builtin(__builtin_amdgcn_mfma_f32_16x16x16bf16_1k)
    return __builtin_amdgcn_mfma_f32_16x16x16bf16_1k(a, b, c, 0, 0, 0);
#else
    asm("v_mfma_f32_16x16x16_bf16 %0, %1, %2, %0" : "+v"(c) : "v"(a), "v"(b));
    return c;
#endif
}

// 16B async global->LDS DMA.  HW semantics: lds dest = lbase + lane*16 (wave-
// uniform base, linear); global src is PER-LANE.  Fallback: synchronous copy.
#if __has_builtin(__builtin_amdgcn_global_load_lds)
#define HAVE_GLL 1
#else
#define HAVE_GLL 0
#endif

static __device__ __forceinline__ void gll16(const void* gp, void* lbase, int lane) {
#if HAVE_GLL
    __builtin_amdgcn_global_load_lds(
        (const __attribute__((address_space(1))) void*)gp,
        (__attribute__((address_space(3))) void*)lbase, 16, 0, 0);
#else
    *(uint4*)((char*)lbase + lane * 16) = *(const uint4*)gp;
#endif
}

// ===========================================================================
// prep: W transpose + mask pre-layout (R2-verified bodies)
// ===========================================================================
static __device__ __forceinline__ void prep_w_job(int job, const float* W0,
                                                  const float* W1, const float* W2,
                                                  bf16* Wt, char* sraw) {
    float(*t)[65] = (float(*)[65])sraw;  // 64*65*4 = 16,640 B
    const int z = job >> 6, sub = job & 63;
    const float* W = (z == 0) ? W0 : (z == 1) ? W1 : W2;
    bf16* O = Wt + (size_t)z * 512 * 512;
    const int d0 = (sub & 7) * 64, n0 = (sub >> 3) * 64;
    {
        int nl = threadIdx.x & 63, dg = threadIdx.x >> 6;
#pragma unroll
        for (int j = 0; j < 16; ++j) {
            int dl = dg + j * 4;
            t[nl][dl] = W[(size_t)(d0 + dl) * 512 + n0 + nl];
        }
    }
    __syncthreads();
    {
        int dl = threadIdx.x & 63, ng = threadIdx.x >> 6;
#pragma unroll
        for (int j = 0; j < 16; ++j) {
            int nl = ng + j * 4;
            O[(size_t)(n0 + nl) * 512 + d0 + dl] = (bf16)t[nl][dl];
        }
    }
}

// mask (512,512) f32 -> Mp bf16 in attn per-lane coalesced order
static __device__ __forceinline__ void prep_mask_job(int bid, const float* maskf,
                                                     bf16* Mp) {
    const int t0 = bid * 256 + threadIdx.x;
    const float4* m4 = (const float4*)maskf;
#pragma unroll
    for (int j = 0; j < 4; ++j) {
        int idx = t0 + j * 16384;
        int q = idx >> 7;
        int sc = idx & 127;
        int cc = sc >> 4;
        int ns = (sc >> 2) & 3;
        int qd = sc & 3;
        float4 v = m4[idx];
        bf16x4 o;
        o[0] = (bf16)v.x; o[1] = (bf16)v.y; o[2] = (bf16)v.z; o[3] = (bf16)v.w;
        size_t off = ((((size_t)(q >> 4) * 8 + cc) * 4 + ns) * 4 + qd) * 64 +
                     (q & 15) * 4;
        *(bf16x4*)&Mp[off] = o;
    }
}

__global__ __launch_bounds__(256) void prep_kernel(const float* W0, const float* W1,
                                                   const float* W2, const float* maskf,
                                                   bf16* Wt, bf16* Mp) {
    __shared__ __align__(16) char sraw[16640];
    if (blockIdx.z == 3) {
        prep_mask_job(blockIdx.y * 8 + blockIdx.x, maskf, Mp);
        return;
    }
    prep_w_job(blockIdx.z * 64 + blockIdx.y * 8 + blockIdx.x, W0, W1, W2, Wt, sraw);
}

// ===========================================================================
// proj v3: 128x128 tile, BK=64, 4 waves 2x2.  vs R2's v1 (67us):
//  - B tile staged by global_load_lds width=16 into an UNPADDED [128][64]
//    tile: no VGPR round-trip, no ds_writes (4 DMA wave-instrs replace
//    4 loads + 4 ds_writes per wave per step).
//  - bank conflicts on the stride-128B B-tile handled by XOR slot swizzle
//    (slot = chunk ^ (row&7)), applied by PRE-SWIZZLING the per-lane global
//    source address (LDS dest stays linear as the DMA requires); the
//    fragment read applies the same XOR.
//  - A (fp32 -> bf16) stays register-staged in padded [128][72] as v1.
//  LDS 34,816 B -> still 4 blocks/CU.  Explicit vmcnt(0) before the
//  publishing barrier guarantees DMA completion.
// ===========================================================================
static __device__ __forceinline__ void proj_job(int j, const float* __restrict__ Xq,
                                                const float* __restrict__ Xk,
                                                const float* __restrict__ Xv,
                                                const bf16* __restrict__ Wt,
                                                bf16* __restrict__ Qw,
                                                bf16* __restrict__ Kw,
                                                bf16* __restrict__ Vt, char* sraw) {
    bf16* la = (bf16*)sraw;         // [128][72] A, padded, reg-staged
    bf16* lb = (bf16*)sraw + 9216;  // [128][64] B, linear, DMA + XOR slots

    const int z = j >> 9, bid = j & 511;
    const float* X = (z == 0) ? Xq : (z == 1) ? Xk : Xv;
    const bf16* W  = Wt + (size_t)z * 512 * 512;
    bf16* Out      = (z == 0) ? Qw : (z == 1) ? Kw : Vt;

    const int tid = threadIdx.x, wave = tid >> 6, lane = tid & 63;
    const int quad = lane >> 4, lc = lane & 15;
    const int wm = wave & 1, wn = wave >> 1;
    // XCD-aware swizzle: 4 n-tiles of one m-tile adjacent on one XCD.
    const int jj = bid >> 3;
    const int yy = jj & 3;
    const int xt = (bid & 7) * 16 + (jj >> 2);
    const int m0 = xt * 128, n0 = yy * 128;

    f32x4 acc[4][4];
#pragma unroll
    for (int ms = 0; ms < 4; ++ms)
#pragma unroll
        for (int ns = 0; ns < 4; ++ns) acc[ms][ns] = (f32x4){0.f, 0.f, 0.f, 0.f};

    const int ar = tid >> 4, ac = tid & 15;
    // B-DMA mapping: wave covers rows wave*8 + i*32 .. +7 per instr (1024 B).
    const int brl   = lane >> 3;          // row within 8-row group
    const int bslot = lane & 7;           // dest 16B slot
    const int bchunk = bslot ^ brl;       // global k-chunk this lane fetches

    float4 xr[8];
#pragma unroll
    for (int i = 0; i < 8; ++i)
        xr[i] = *(const float4*)&X[(size_t)(m0 + ar + i * 16) * 512 + ac * 4];

    for (int kb = 0; kb < 512; kb += 64) {
        __syncthreads();  // (1) all waves done reading la/lb of previous step
        // issue B(kb) DMA: 4 wave-instrs, dest linear, src pre-swizzled
#pragma unroll
        for (int i = 0; i < 4; ++i) {
            int rgrp = wave * 8 + i * 32;
            gll16(&W[(size_t)(n0 + rgrp + brl) * 512 + kb + bchunk * 8],
                  lb + (size_t)rgrp * 64, lane);
        }
        // stage A(kb) from prefetched regs (fp32 -> bf16)
#pragma unroll
        for (int i = 0; i < 8; ++i) {
            float4 x = xr[i];
            bf16x4 p;
            p[0] = (bf16)x.x; p[1] = (bf16)x.y; p[2] = (bf16)x.z; p[3] = (bf16)x.w;
            *(bf16x4*)&la[(ar + i * 16) * 72 + ac * 4] = p;
        }
#if HAVE_GLL
        asm volatile("s_waitcnt vmcnt(0)" ::: "memory");  // B(kb) landed
#endif
        __syncthreads();  // (2) la+lb published
        if (kb < 448) {
            int kn = kb + 64;
#pragma unroll
            for (int i = 0; i < 8; ++i)
                xr[i] = *(const float4*)&X[(size_t)(m0 + ar + i * 16) * 512 + kn + ac * 4];
        }
#pragma unroll
        for (int kk = 0; kk < 2; ++kk) {
            bf16x8 af[4], bfr[4];
#pragma unroll
            for (int ms = 0; ms < 4; ++ms)
                af[ms] = *(bf16x8*)&la[(wm * 64 + ms * 16 + lc) * 72 + kk * 32 + quad * 8];
#pragma unroll
            for (int ns = 0; ns < 4; ++ns) {
                int row = wn * 64 + ns * 16 + lc;
                int slot = (kk * 4 + quad) ^ (lc & 7);  // row&7 == lc&7
                bfr[ns] = *(bf16x8*)&lb[(size_t)row * 64 + slot * 8];
            }
#pragma unroll
            for (int ms = 0; ms < 4; ++ms)
#pragma unroll
                for (int ns = 0; ns < 4; ++ns)
                    acc[ms][ns] = __builtin_amdgcn_mfma_f32_16x16x32_bf16(
                        af[ms], bfr[ns], acc[ms][ns], 0, 0, 0);
        }
    }
    // --- epilogue (R2-verified) ---
    __syncthreads();
    bf16* lds_c = (bf16*)sraw;  // z<2: [m][n] 128x136 ; z==2: [n][m] 128x136
    if (z != 2) {
#pragma unroll
        for (int ms = 0; ms < 4; ++ms)
#pragma unroll
            for (int ns = 0; ns < 4; ++ns)
#pragma unroll
                for (int r = 0; r < 4; ++r)
                    lds_c[(wm * 64 + ms * 16 + quad * 4 + r) * 136 +
                          wn * 64 + ns * 16 + lc] = (bf16)acc[ms][ns][r];
    } else {
#pragma unroll
        for (int ms = 0; ms < 4; ++ms)
#pragma unroll
            for (int ns = 0; ns < 4; ++ns)
#pragma unroll
                for (int r = 0; r < 4; ++r)
                    lds_c[(wn * 64 + ns * 16 + lc) * 136 +
                          wm * 64 + ms * 16 + quad * 4 + r] = (bf16)acc[ms][ns][r];
    }
    __syncthreads();
    const int bt = m0 >> 9, l0 = m0 & 511;
    if (z != 2) {
        const int ec = tid & 7, rg = tid >> 3;
#pragma unroll
        for (int hc = 0; hc < 2; ++hc) {
            int h = (n0 >> 6) + hc;
#pragma unroll
            for (int p = 0; p < 4; ++p) {
                int row = rg + p * 32;
                bf16x8 v = *(bf16x8*)&lds_c[row * 136 + hc * 64 + ec * 8];
                *(bf16x8*)&Out[(((size_t)bt * 8 + h) * 512 + l0 + row) * 64 + ec * 8] = v;
            }
        }
    } else {
        const int rowp = lane >> 2, cc = lane & 3;
#pragma unroll
        for (int pr = 0; pr < 2; ++pr) {
            int row = wave * 32 + pr * 16 + rowp;
            int h = (n0 >> 6) + (row >> 6);
            int e = row & 63;
            bf16* dst = Out + (((size_t)bt * 8 + h) * 64 + e) * 512 + l0;
#pragma unroll
            for (int pc = 0; pc < 4; ++pc) {
                int mc = cc + pc * 4;
                *(bf16x8*)&dst[mc * 8] = *(bf16x8*)&lds_c[row * 136 + mc * 8];
            }
        }
    }
}

__global__ __launch_bounds__(256) void proj_kernel(const float* Xq, const float* Xk,
                                                   const float* Xv, const bf16* Wt,
                                                   bf16* Qw, bf16* Kw, bf16* Vt) {
    __shared__ __align__(16) char sraw[34816];
    int j = blockIdx.z * 512 + blockIdx.y * 128 + blockIdx.x;
    proj_job(j, Xq, Xk, Xv, Wt, Qw, Kw, Vt, sraw);
}

// ===========================================================================
// attn (R2-verified v9: mask pre-layout, in-register P->PV via 16x16x16,
// K/V double-buffer, 1 barrier/chunk, NO setprio).
// mode 0: atomicAdd.  mode 1: f32 partials.  mode 2: f16 partials.
// ===========================================================================
__global__ __launch_bounds__(256, 4) void attn_kernel(
    const bf16* __restrict__ Qw, const bf16* __restrict__ Kw,
    const bf16* __restrict__ Vt, const bf16* __restrict__ Mp,
    const float* __restrict__ w_head, const float* __restrict__ tau,
    const float* __restrict__ delta, float* __restrict__ out,
    void* __restrict__ opart, int mode) {
    __shared__ __align__(16) bf16 lds_k[2][64 * 72];   // [s][e], pad 8
    __shared__ __align__(16) bf16 lds_vt[2][64 * 72];  // [e][s], pad 8

    const int tid  = threadIdx.x;
    const int wave = tid >> 6;
    const int lane = tid & 63;
    const int quad = lane >> 4;
    const int lc   = lane & 15;
    const int b    = blockIdx.x;
    const int bth  = b & 255;
    const int qquad = b >> 8;
    const int bt   = bth >> 3;
    const int h    = bth & 7;

    const bf16* Qh  = Qw + (size_t)bth * (512 * 64);
    const bf16* Kh  = Kw + (size_t)bth * (512 * 64);
    const bf16* VtH = Vt + (size_t)bth * (512 * 64);

    const float L2E = 1.4426950408889634f;
    const float ts = tau[0] * 0.125f * L2E;
    const float ds = delta[0] * 0.125f * L2E;
    const float wh = w_head[h];

    const int q0 = qquad * 128 + wave * 32;
    const size_t mbA = (size_t)(q0 >> 4) * 8192 + lane * 4;
    const size_t mbB = mbA + 8192;

    bf16x8 qfA[2], qfB[2];
#pragma unroll
    for (int kk = 0; kk < 2; ++kk) {
        qfA[kk] = *(const bf16x8*)&Qh[(size_t)(q0 + lc) * 64 + kk * 32 + quad * 8];
        qfB[kk] = *(const bf16x8*)&Qh[(size_t)(q0 + 16 + lc) * 64 + kk * 32 + quad * 8];
    }

    f32x4 oA[4], oB[4];
#pragma unroll
    for (int ns = 0; ns < 4; ++ns) {
        oA[ns] = (f32x4){0.f, 0.f, 0.f, 0.f};
        oB[ns] = (f32x4){0.f, 0.f, 0.f, 0.f};
    }
    float lA = 0.f, lB = 0.f;

    const int srow = tid >> 3, scc = tid & 7;
    bf16x8 kr[2], vr[2];
    kr[0] = *(const bf16x8*)&Kh[(size_t)srow * 64 + scc * 8];
    kr[1] = *(const bf16x8*)&Kh[(size_t)(srow + 32) * 64 + scc * 8];
    vr[0] = *(const bf16x8*)&VtH[(size_t)srow * 512 + scc * 8];
    vr[1] = *(const bf16x8*)&VtH[(size_t)(srow + 32) * 512 + scc * 8];
    *(bf16x8*)&lds_k[0][srow * 72 + scc * 8] = kr[0];
    *(bf16x8*)&lds_k[0][(srow + 32) * 72 + scc * 8] = kr[1];
    *(bf16x8*)&lds_vt[0][srow * 72 + scc * 8] = vr[0];
    *(bf16x8*)&lds_vt[0][(srow + 32) * 72 + scc * 8] = vr[1];
    kr[0] = *(const bf16x8*)&Kh[(size_t)(64 + srow) * 64 + scc * 8];
    kr[1] = *(const bf16x8*)&Kh[(size_t)(64 + srow + 32) * 64 + scc * 8];
    vr[0] = *(const bf16x8*)&VtH[(size_t)srow * 512 + 64 + scc * 8];
    vr[1] = *(const bf16x8*)&VtH[(size_t)(srow + 32) * 512 + 64 + scc * 8];

    for (int c = 0; c < 8; ++c) {
        const int buf = c & 1;
        __syncthreads();
        bf16x4 mA[4], mB[4];
        {
            const size_t mc = mbA + (size_t)c * 1024;
            const size_t md = mbB + (size_t)c * 1024;
#pragma unroll
            for (int ns = 0; ns < 4; ++ns) {
                mA[ns] = *(const bf16x4*)&Mp[mc + ns * 256];
                mB[ns] = *(const bf16x4*)&Mp[md + ns * 256];
            }
        }
        f32x4 stA[4], stB[4];
#pragma unroll
        for (int ns = 0; ns < 4; ++ns) {
            stA[ns] = (f32x4){0.f, 0.f, 0.f, 0.f};
            stB[ns] = (f32x4){0.f, 0.f, 0.f, 0.f};
        }
#pragma unroll
        for (int kk = 0; kk < 2; ++kk)
#pragma unroll
            for (int ns = 0; ns < 4; ++ns) {
                bf16x8 ka = *(bf16x8*)&lds_k[buf][(ns * 16 + lc) * 72 + kk * 32 + quad * 8];
                stA[ns] = __builtin_amdgcn_mfma_f32_16x16x32_bf16(ka, qfA[kk], stA[ns], 0, 0, 0);
                stB[ns] = __builtin_amdgcn_mfma_f32_16x16x32_bf16(ka, qfB[kk], stB[ns], 0, 0, 0);
            }
        if (c < 7) {
            const int nb = buf ^ 1;
            *(bf16x8*)&lds_k[nb][srow * 72 + scc * 8] = kr[0];
            *(bf16x8*)&lds_k[nb][(srow + 32) * 72 + scc * 8] = kr[1];
            *(bf16x8*)&lds_vt[nb][srow * 72 + scc * 8] = vr[0];
            *(bf16x8*)&lds_vt[nb][(srow + 32) * 72 + scc * 8] = vr[1];
            if (c < 6) {
                const int s0n = (c + 2) * 64;
                kr[0] = *(const bf16x8*)&Kh[(size_t)(s0n + srow) * 64 + scc * 8];
                kr[1] = *(const bf16x8*)&Kh[(size_t)(s0n + srow + 32) * 64 + scc * 8];
                vr[0] = *(const bf16x8*)&VtH[(size_t)srow * 512 + s0n + scc * 8];
                vr[1] = *(const bf16x8*)&VtH[(size_t)(srow + 32) * 512 + s0n + scc * 8];
            }
        }
        bf16x4 paA[4], paB[4];
#pragma unroll
        for (int ns = 0; ns < 4; ++ns) {
#pragma unroll
            for (int r = 0; r < 4; ++r) {
                float eA = (stA[ns][r] * ts + ds) * (float)mA[ns][r];
                float eB = (stB[ns][r] * ts + ds) * (float)mB[ns][r];
                float pA = EXP2(eA);
                float pB = EXP2(eB);
                lA += pA; lB += pB;
                paA[ns][r] = (bf16)pA;
                paB[ns][r] = (bf16)pB;
            }
        }
#pragma unroll
        for (int ks = 0; ks < 4; ++ks)
#pragma unroll
            for (int ns = 0; ns < 4; ++ns) {
                bf16x4 vv = *(bf16x4*)&lds_vt[buf][(ns * 16 + lc) * 72 + ks * 16 + quad * 4];
                oA[ns] = mfma16(paA[ks], vv, oA[ns]);
                oB[ns] = mfma16(paB[ks], vv, oB[ns]);
            }
    }
    lA += __shfl_xor(lA, 16, 64);
    lA += __shfl_xor(lA, 32, 64);
    lB += __shfl_xor(lB, 16, 64);
    lB += __shfl_xor(lB, 32, 64);
#pragma unroll
    for (int r = 0; r < 4; ++r) {
        float lrA = __shfl(lA, quad * 4 + r, 64);
        float lrB = __shfl(lB, quad * 4 + r, 64);
        float ivA = wh / lrA, ivB = wh / lrB;
        int qqA = q0 + quad * 4 + r;
        int qqB = q0 + 16 + quad * 4 + r;
        if (mode == 0) {
#pragma unroll
            for (int ns = 0; ns < 4; ++ns) {
                int e = ns * 16 + lc;
                atomicAdd(&out[((size_t)bt * 512 + qqA) * 64 + e], oA[ns][r] * ivA);
                atomicAdd(&out[((size_t)bt * 512 + qqB) * 64 + e], oB[ns][r] * ivB);
            }
        } else if (mode == 1) {
            float* op = (float*)opart;
#pragma unroll
            for (int ns = 0; ns < 4; ++ns) {
                int e = ns * 16 + lc;
                op[((size_t)bth * 512 + qqA) * 64 + e] = oA[ns][r] * ivA;
                op[((size_t)bth * 512 + qqB) * 64 + e] = oB[ns][r] * ivB;
            }
        } else {
            _Float16* op = (_Float16*)opart;
#pragma unroll
            for (int ns = 0; ns < 4; ++ns) {
                int e = ns * 16 + lc;
                op[((size_t)bth * 512 + qqA) * 64 + e] = (_Float16)(oA[ns][r] * ivA);
                op[((size_t)bth * 512 + qqB) * 64 + e] = (_Float16)(oB[ns][r] * ivB);
            }
        }
    }
}

// ===========================================================================
// reduce: out[bt][q][e] = sum_h Opart[bt*8+h][q][e]
// ===========================================================================
__global__ __launch_bounds__(256) void reduce_kernel(const void* __restrict__ part,
                                                     float* __restrict__ out,
                                                     int mode) {
    const int idx = blockIdx.x * 256 + threadIdx.x;
    const int bt = idx >> 13;
    const int rf = idx & 8191;
    f32x4 s = (f32x4){0.f, 0.f, 0.f, 0.f};
    if (mode == 1) {
        const f32x4* p = (const f32x4*)part + (size_t)bt * 65536 + rf;
#pragma unroll
        for (int h = 0; h < 8; ++h) s += p[(size_t)h * 8192];
    } else {
        const half4* p = (const half4*)part + (size_t)bt * 65536 + rf;
#pragma unroll
        for (int h = 0; h < 8; ++h) {
            half4 v = p[(size_t)h * 8192];
            s[0] += (float)v[0]; s[1] += (float)v[1];
            s[2] += (float)v[2]; s[3] += (float)v[3];
        }
    }
    *(f32x4*)&out[(size_t)idx * 4] = s;
}

// ---------------------------------------------------------------------------
extern "C" void kernel_launch(void* const* d_in, const int* in_sizes, int n_in,
                              void* d_out, int out_size, void* d_ws, size_t ws_size,
                              hipStream_t stream) {
    const float* queries = (const float*)d_in[0];
    const float* keys    = (const float*)d_in[1];
    const float* values  = (const float*)d_in[2];
    const float* mask    = (const float*)d_in[3];
    const float* Wq      = (const float*)d_in[4];
    const float* Wk      = (const float*)d_in[5];
    const float* Wv      = (const float*)d_in[6];
    const float* w_head  = (const float*)d_in[7];
    const float* tau     = (const float*)d_in[8];
    const float* delta   = (const float*)d_in[9];

    char* ws = (char*)d_ws;
    bf16* Qw = (bf16*)(ws);                    // 16,777,216 B
    bf16* Kw = (bf16*)(ws + 16777216ull);      // 16,777,216 B
    bf16* Vt = (bf16*)(ws + 33554432ull);      // 16,777,216 B (V^T [bth][e][s])
    bf16* Wt = (bf16*)(ws + 50331648ull);      //  1,572,864 B
    bf16* Mp = (bf16*)(ws + 51904512ull);      //    524,288 B
    char* Op = ws + 52428800ull;               // partials (f32 33.5MB / f16 16.8MB)

    // mode: 1 = f32 partials (R2-verified config), 2 = f16, 0 = atomic fallback
    int mode = (ws_size >= 52428800ull + 33554432ull) ? 1
             : (ws_size >= 52428800ull + 16777216ull) ? 2 : 0;

    if (mode == 0)
        hipMemsetAsync(d_out, 0, (size_t)out_size * sizeof(float), stream);

    prep_kernel<<<dim3(8, 8, 4), 256, 0, stream>>>(Wq, Wk, Wv, mask, Wt, Mp);

    proj_kernel<<<dim3(128, 4, 3), 256, 0, stream>>>(queries, keys, values, Wt,
                                                     Qw, Kw, Vt);

    attn_kernel<<<1024, 256, 0, stream>>>(Qw, Kw, Vt, Mp, w_head, tau, delta,
                                          (float*)d_out, (void*)Op, mode);

    if (mode != 0)
        reduce_kernel<<<1024, 256, 0, stream>>>((const void*)Op, (float*)d_out,
                                                mode);
}